// Round 1
// baseline (424.786 us; speedup 1.0000x reference)
//
#include <hip/hip_runtime.h>

#define S_U 256
#define N_IMP 128
#define OUT_STRIDE (4 + N_IMP)

// truncation = 2/512*4
#define TRUNC 0.015625f

__global__ __launch_bounds__(256) void tsdf_render_kernel(
    const float* __restrict__ occ,
    const float* __restrict__ zvals,
    const float* __restrict__ sdf,
    const float* __restrict__ rgbs,
    float* __restrict__ out)
{
    const int ray = blockIdx.x;
    const int tid = threadIdx.x;

    __shared__ float s_scan[S_U];       // scan buffer (reused)
    __shared__ float s_z[S_U];          // z_vals
    __shared__ float s_zmid[S_U];       // [0..254] bin midpoints
    __shared__ float s_cdf[S_U];        // [0..254]
    __shared__ float s_wu[S_U];         // coarse weights
    __shared__ float s_zs[N_IMP];       // importance samples
    __shared__ float s_sdf[N_IMP];
    __shared__ float s_rgb[N_IMP * 3];
    __shared__ float s_red1[N_IMP];
    __shared__ float4 s_red4[N_IMP];
    __shared__ int s_cross;

    // ---- global loads (all coalesced) ----
    const float* occ_r = occ + (size_t)ray * S_U;
    const float* z_r   = zvals + (size_t)ray * S_U;
    float o = occ_r[tid];
    s_z[tid] = z_r[tid];
    if (tid < (N_IMP * 3) / 4) {  // 96 threads x float4 = 384 floats
        ((float4*)s_rgb)[tid] = ((const float4*)(rgbs + (size_t)ray * (N_IMP * 3)))[tid];
    }
    float sv = 0.0f;
    if (tid < N_IMP) {
        sv = sdf[(size_t)ray * N_IMP + tid];
        s_sdf[tid] = sv;
    }
    if (tid == 0) s_cross = 0x7fffffff;

    // ---- occupancy alpha ----
    float a_u = 1.0f / (1.0f + expf(-10.0f * o));
    s_scan[tid] = 1.0f - a_u + 1e-10f;
    __syncthreads();

    if (tid < S_U - 1) s_zmid[tid] = 0.5f * (s_z[tid] + s_z[tid + 1]);

    // ---- inclusive product scan (Hillis-Steele) -> transmittance ----
    for (int off = 1; off < S_U; off <<= 1) {
        float v = (tid >= off) ? s_scan[tid - off] : 1.0f;
        __syncthreads();
        if (tid >= off) s_scan[tid] *= v;
        __syncthreads();
    }
    float trans = (tid == 0) ? 1.0f : s_scan[tid - 1];  // exclusive
    float w_u = a_u * trans;
    s_wu[tid] = w_u;
    __syncthreads();

    // ---- CDF over w_u[1..254]+1e-5 (254 values, 255 bins) ----
    float wv = (tid < S_U - 2) ? (s_wu[tid + 1] + 1e-5f) : 0.0f;
    s_scan[tid] = wv;   // safe: all prior s_scan reads were before last sync
    __syncthreads();
    for (int off = 1; off < S_U; off <<= 1) {
        float v = (tid >= off) ? s_scan[tid - off] : 0.0f;
        __syncthreads();
        if (tid >= off) s_scan[tid] += v;
        __syncthreads();
    }
    float total = s_scan[S_U - 3];      // index 253 = sum of all 254 values
    float inv_total = 1.0f / total;
    if (tid == 0) s_cdf[0] = 0.0f;
    if (tid < S_U - 2) s_cdf[tid + 1] = s_scan[tid] * inv_total;
    __syncthreads();

    // ---- inverse-CDF deterministic sampling (upper_bound == side='right') ----
    float zs = 0.0f;
    if (tid < N_IMP) {
        float u = (float)tid / 127.0f;  // linspace(0,1,128); tid=127 -> exactly 1.0
        int lo = 0, hi = 255;
        while (lo < hi) {
            int mid = (lo + hi) >> 1;
            if (s_cdf[mid] <= u) lo = mid + 1; else hi = mid;
        }
        int below = lo - 1; if (below < 0) below = 0;
        int above = lo;     if (above > 254) above = 254;
        float cb = s_cdf[below], ca = s_cdf[above];
        float zb = s_zmid[below], za = s_zmid[above];
        float denom = ca - cb;
        if (denom < 1e-5f) denom = 1.0f;
        float t = (u - cb) / denom;
        zs = zb + t * (za - zb);
        s_zs[tid] = zs;
    }
    __syncthreads();

    // ---- first zero-crossing of sdf (argmax of sign mask; 0 if none) ----
    if (tid < N_IMP - 1) {
        if (sv * s_sdf[tid + 1] < 0.0f) atomicMin(&s_cross, tid);
    }
    __syncthreads();
    int ci = s_cross; if (ci == 0x7fffffff) ci = 0;
    float z_min = s_zs[ci];

    // ---- TSDF alpha + truncation mask ----
    float alpha = 0.0f;
    if (tid < N_IMP) {
        float x = sv * (1.0f / TRUNC);
        // sigmoid(x)*sigmoid(-x) = 1/(2 + e^x + e^-x)
        float a = 1.0f / (2.0f + expf(x) + expf(-x));
        if (!(zs < z_min + TRUNC)) a = 0.0f;
        alpha = a;
    }
    if (tid < N_IMP) s_red1[tid] = alpha;
    __syncthreads();
    for (int off = N_IMP / 2; off > 0; off >>= 1) {
        if (tid < off) s_red1[tid] += s_red1[tid + off];
        __syncthreads();
    }
    float suma = s_red1[0];
    float wgt = alpha / (suma + 1e-8f);

    // ---- composite ----
    if (tid < N_IMP) {
        out[(size_t)ray * OUT_STRIDE + 4 + tid] = wgt;
        float r = s_rgb[tid * 3 + 0];
        float g = s_rgb[tid * 3 + 1];
        float b = s_rgb[tid * 3 + 2];
        s_red4[tid] = make_float4(wgt * r, wgt * g, wgt * b, wgt * zs);
    }
    __syncthreads();
    for (int off = N_IMP / 2; off > 0; off >>= 1) {
        if (tid < off) {
            float4 x1 = s_red4[tid];
            float4 x2 = s_red4[tid + off];
            s_red4[tid] = make_float4(x1.x + x2.x, x1.y + x2.y, x1.z + x2.z, x1.w + x2.w);
        }
        __syncthreads();
    }
    if (tid == 0) {
        float4 r = s_red4[0];
        float* ob = out + (size_t)ray * OUT_STRIDE;
        ob[0] = fminf(fmaxf(r.x, 0.0f), 1.0f);
        ob[1] = fminf(fmaxf(r.y, 0.0f), 1.0f);
        ob[2] = fminf(fmaxf(r.z, 0.0f), 1.0f);
        ob[3] = r.w;
    }
}

extern "C" void kernel_launch(void* const* d_in, const int* in_sizes, int n_in,
                              void* d_out, int out_size, void* d_ws, size_t ws_size,
                              hipStream_t stream) {
    const float* occ  = (const float*)d_in[0];
    const float* z    = (const float*)d_in[1];
    const float* sdf  = (const float*)d_in[2];
    const float* rgbs = (const float*)d_in[3];
    float* out = (float*)d_out;
    const int n_rays = in_sizes[0] / S_U;
    hipLaunchKernelGGL(tsdf_render_kernel, dim3(n_rays), dim3(S_U), 0, stream,
                       occ, z, sdf, rgbs, out);
}

// Round 2
// 263.634 us; speedup vs baseline: 1.6113x; 1.6113x over previous
//
#include <hip/hip_runtime.h>

#define S_U 256
#define N_IMP 128
#define OUT_STRIDE (4 + N_IMP)
#define TRUNC 0.015625f   // 2/512*4
#define WPB 4             // waves (= rays) per 256-thread block

__device__ __forceinline__ float inv_cdf_sample(const float* __restrict__ cdf,
                                                const float* __restrict__ zm,
                                                float u) {
    // searchsorted(cdf[0..254], u, side='right') via 8-step binary search
    int lo = 0, hi = 255;
#pragma unroll
    for (int it = 0; it < 8; ++it) {
        int mid = (lo + hi) >> 1;
        bool c = cdf[mid] <= u;
        lo = c ? mid + 1 : lo;
        hi = c ? hi : mid;
    }
    int below = max(lo - 1, 0);
    int above = min(lo, 254);
    float cb = cdf[below], ca = cdf[above];
    float zb = zm[below],  za = zm[above];
    float denom = ca - cb;
    denom = (denom < 1e-5f) ? 1.0f : denom;
    float t = (u - cb) / denom;
    return zb + t * (za - zb);
}

__global__ __launch_bounds__(256) void tsdf_render_kernel(
    const float* __restrict__ occ,
    const float* __restrict__ zvals,
    const float* __restrict__ sdf,
    const float* __restrict__ rgbs,
    float* __restrict__ out)
{
    const int lane = threadIdx.x & 63;
    const int wv   = threadIdx.x >> 6;
    const int ray  = blockIdx.x * WPB + wv;

    __shared__ __align__(16) float s_cdf [WPB][S_U];
    __shared__ __align__(16) float s_zmid[WPB][S_U];

    // ---------------- coarse loads (float4, fully coalesced) ----------------
    const float4 o4 = ((const float4*)(occ   + (size_t)ray * S_U))[lane];
    const float4 z4 = ((const float4*)(zvals + (size_t)ray * S_U))[lane];

    // occupancy alpha
    float a0 = 1.0f / (1.0f + __expf(-10.0f * o4.x));
    float a1 = 1.0f / (1.0f + __expf(-10.0f * o4.y));
    float a2 = 1.0f / (1.0f + __expf(-10.0f * o4.z));
    float a3 = 1.0f / (1.0f + __expf(-10.0f * o4.w));
    float t0 = 1.0f - a0 + 1e-10f;
    float t1 = 1.0f - a1 + 1e-10f;
    float t2 = 1.0f - a2 + 1e-10f;
    float t3 = 1.0f - a3 + 1e-10f;

    // lane-local cumulative products, then wave product-scan of lane totals
    float pp0 = t0, pp1 = pp0 * t1, pp2 = pp1 * t2, pp3 = pp2 * t3;
    float ip = pp3;
#pragma unroll
    for (int d = 1; d < 64; d <<= 1) {
        float y = __shfl_up(ip, d);
        if (lane >= d) ip *= y;
    }
    float pbase = __shfl_up(ip, 1);
    if (lane == 0) pbase = 1.0f;

    // coarse weights w_u[i] = alpha[i] * prod_{k<i}(1-alpha+1e-10)
    float w0 = a0 * pbase;
    float w1 = a1 * pbase * pp0;
    float w2 = a2 * pbase * pp1;
    float w3 = a3 * pbase * pp2;

    // ---------------- CDF over w_u[1..254] + 1e-5 ----------------
    float v0 = (lane > 0)  ? w0 + 1e-5f : 0.0f;   // i = 4*lane
    float v1 = w1 + 1e-5f;                         // i = 4*lane+1 (1..253)
    float v2 = w2 + 1e-5f;                         // i = 4*lane+2 (2..254)
    float v3 = (lane < 63) ? w3 + 1e-5f : 0.0f;   // i = 4*lane+3 (255 excluded)
    float s0 = v0, s1 = s0 + v1, s2 = s1 + v2, s3 = s2 + v3;
    float is = s3;
#pragma unroll
    for (int d = 1; d < 64; d <<= 1) {
        float y = __shfl_up(is, d);
        if (lane >= d) is += y;
    }
    float total = __shfl(is, 63);
    float sbase = __shfl_up(is, 1);
    if (lane == 0) sbase = 0.0f;
    float invt = 1.0f / total;

    float4 cdf4;
    cdf4.x = (sbase + s0) * invt;
    cdf4.y = (sbase + s1) * invt;
    cdf4.z = (sbase + s2) * invt;
    cdf4.w = (sbase + s3) * invt;
    *((float4*)&s_cdf[wv][lane * 4]) = cdf4;

    // z midpoints
    float znext = __shfl_down(z4.x, 1);
    float4 zm4;
    zm4.x = 0.5f * (z4.x + z4.y);
    zm4.y = 0.5f * (z4.y + z4.z);
    zm4.z = 0.5f * (z4.z + z4.w);
    zm4.w = 0.5f * (z4.w + znext);   // lane 63: garbage, index 255 never read
    *((float4*)&s_zmid[wv][lane * 4]) = zm4;

    __builtin_amdgcn_wave_barrier();  // pin LDS write->read order (intra-wave, no hw barrier)

    // ---------------- importance sampling: 2 samples / lane ----------------
    const float2 sd2 = ((const float2*)(sdf + (size_t)ray * N_IMP))[lane];
    const float2* rg = (const float2*)(rgbs + (size_t)ray * (N_IMP * 3)) + lane * 3;
    float2 p0 = rg[0];   // r0 g0
    float2 p1 = rg[1];   // b0 r1
    float2 p2 = rg[2];   // g1 b1

    const float* cdfp = s_cdf[wv];
    const float* zmp  = s_zmid[wv];
    float u0 = (float)(2 * lane)     * (1.0f / 127.0f);
    float u1 = (float)(2 * lane + 1) * (1.0f / 127.0f);
    float zs0 = inv_cdf_sample(cdfp, zmp, u0);
    float zs1 = inv_cdf_sample(cdfp, zmp, u1);

    // ---------------- first zero-crossing of sdf ----------------
    float sn = __shfl_down(sd2.x, 1);   // sdf[2*lane+2]
    int c = 0x7fffffff;
    if (sd2.x * sd2.y < 0.0f)                     c = 2 * lane;
    else if (lane < 63 && sd2.y * sn < 0.0f)      c = 2 * lane + 1;
#pragma unroll
    for (int d = 32; d > 0; d >>= 1) c = min(c, __shfl_xor(c, d));
    int ci = (c == 0x7fffffff) ? 0 : c;
    float zca = __shfl(zs0, ci >> 1);
    float zcb = __shfl(zs1, ci >> 1);
    float z_min = (ci & 1) ? zcb : zca;

    // ---------------- TSDF alpha + truncation mask ----------------
    float x0 = sd2.x * (1.0f / TRUNC);
    float x1 = sd2.y * (1.0f / TRUNC);
    // sigmoid(x)*sigmoid(-x) = 1/(2 + e^x + e^-x)
    float al0 = 1.0f / (2.0f + __expf(x0) + __expf(-x0));
    float al1 = 1.0f / (2.0f + __expf(x1) + __expf(-x1));
    float zlim = z_min + TRUNC;
    if (!(zs0 < zlim)) al0 = 0.0f;
    if (!(zs1 < zlim)) al1 = 0.0f;

    float asum = al0 + al1;
#pragma unroll
    for (int d = 32; d > 0; d >>= 1) asum += __shfl_xor(asum, d);
    float inv_s = 1.0f / (asum + 1e-8f);
    float g0 = al0 * inv_s;
    float g1 = al1 * inv_s;

    // ---------------- composite ----------------
    float rr = g0 * p0.x + g1 * p1.y;
    float gg = g0 * p0.y + g1 * p2.x;
    float bb = g0 * p1.x + g1 * p2.y;
    float dd = g0 * zs0  + g1 * zs1;
#pragma unroll
    for (int d = 32; d > 0; d >>= 1) {
        rr += __shfl_xor(rr, d);
        gg += __shfl_xor(gg, d);
        bb += __shfl_xor(bb, d);
        dd += __shfl_xor(dd, d);
    }

    float* ob = out + (size_t)ray * OUT_STRIDE;
    ((float2*)(ob + 4))[lane] = make_float2(g0, g1);
    if (lane == 0) {
        ob[0] = fminf(fmaxf(rr, 0.0f), 1.0f);
        ob[1] = fminf(fmaxf(gg, 0.0f), 1.0f);
        ob[2] = fminf(fmaxf(bb, 0.0f), 1.0f);
        ob[3] = dd;
    }
}

extern "C" void kernel_launch(void* const* d_in, const int* in_sizes, int n_in,
                              void* d_out, int out_size, void* d_ws, size_t ws_size,
                              hipStream_t stream) {
    const float* occ  = (const float*)d_in[0];
    const float* z    = (const float*)d_in[1];
    const float* sdf  = (const float*)d_in[2];
    const float* rgbs = (const float*)d_in[3];
    float* out = (float*)d_out;
    const int n_rays = in_sizes[0] / S_U;
    hipLaunchKernelGGL(tsdf_render_kernel, dim3(n_rays / WPB), dim3(256), 0, stream,
                       occ, z, sdf, rgbs, out);
}